// Round 1
// baseline (438.704 us; speedup 1.0000x reference)
//
#include <hip/hip_runtime.h>
#include <hip/hip_fp16.h>

#define NFEAT 128
#define NCHUNK 8
#define CFEAT 16   // features per chunk; NCHUNK*CFEAT == NFEAT

typedef _Float16 v8hf __attribute__((ext_vector_type(8)));
typedef float v4f __attribute__((ext_vector_type(4)));

// ------- degree histogram + per-edge rank (incl. self edges) + W prep --------
__global__ void k_deg_rank_w(const int* __restrict__ dst, int* __restrict__ deg,
                             int* __restrict__ rank, int E, int N,
                             const float* __restrict__ W1, const float* __restrict__ W2,
                             _Float16* __restrict__ Wt1, _Float16* __restrict__ Wt2) {
  int e = blockIdx.x * blockDim.x + threadIdx.x;
  if (e < E) rank[e] = atomicAdd(&deg[dst[e]], 1);
  else if (e < E + N) rank[e] = atomicAdd(&deg[e - E], 1);
  else if (e < E + N + 32768) {
    int idx = e - E - N;             // 0..32767
    const float* W = (idx < 16384) ? W1 : W2;
    _Float16* Wt = (idx < 16384) ? Wt1 : Wt2;
    int i = idx & 16383;
    int k = i >> 7, n = i & 127;
    Wt[n * 128 + k] = (_Float16)W[k * 128 + n];
  }
}

// ---------------- 2-level exclusive scan over degrees ------------------------
__global__ __launch_bounds__(1024) void k_scan_blocks(const int* __restrict__ deg,
    int* __restrict__ base, int* __restrict__ partials, int n) {
  __shared__ int buf[1024];
  int tid = threadIdx.x;
  int i = blockIdx.x * 1024 + tid;
  int v = (i < n) ? deg[i] : 0;
  buf[tid] = v;
  __syncthreads();
  #pragma unroll
  for (int off = 1; off < 1024; off <<= 1) {
    int t = (tid >= off) ? buf[tid - off] : 0;
    __syncthreads();
    buf[tid] += t;
    __syncthreads();
  }
  if (i <= n) base[i] = buf[tid] - v;
  if (tid == 1023) partials[blockIdx.x] = buf[tid];
}

__global__ void k_scan_partials(int* __restrict__ partials, int nb) {
  __shared__ int buf[128];
  int tid = threadIdx.x;
  int v = (tid < nb) ? partials[tid] : 0;
  buf[tid] = v;
  __syncthreads();
  #pragma unroll
  for (int off = 1; off < 128; off <<= 1) {
    int t = (tid >= off) ? buf[tid - off] : 0;
    __syncthreads();
    buf[tid] += t;
    __syncthreads();
  }
  if (tid < nb) partials[tid] = buf[tid] - v;
}

__global__ void k_finalize_base(int* __restrict__ base, const int* __restrict__ partials,
    const int* __restrict__ deg, float* __restrict__ dinv, int n) {
  int i = blockIdx.x * blockDim.x + threadIdx.x;
  if (i <= n) {
    base[i] += partials[i >> 10];
    if (i < n) dinv[i] = rsqrtf((float)deg[i]);   // deg already includes self
  }
}

__global__ void k_scatter(const int* __restrict__ src, const int* __restrict__ dst,
    const int* __restrict__ rank, const int* __restrict__ base,
    int* __restrict__ ssrc, int E, int N) {
  int e = blockIdx.x * blockDim.x + threadIdx.x;
  if (e < E) ssrc[base[dst[e]] + rank[e]] = src[e];
  else if (e < E + N) { int n = e - E; ssrc[base[n] + rank[e]] = n; }
}

// ---------------- MFMA fp16 GEMM ---------------------------------------------
// Output is CHUNK-MAJOR: g16[chunk][N+1][CFEAT], chunk = 16-column tile.
// Each chunk slice is a contiguous 3.2 MB block so one XCD's L2 can hold it
// during aggregation and cache lines never mix chunks.
template <typename AT>
__global__ __launch_bounds__(256) void k_gemm_mfma(
    const AT* __restrict__ A, const _Float16* __restrict__ Wt,
    const float* __restrict__ dinv, _Float16* __restrict__ g16, int N) {
  __shared__ _Float16 As[64][136];
  __shared__ _Float16 Ws[128][136];
  const int tid = threadIdx.x;
  const int row0 = blockIdx.x * 64;

  if (blockIdx.x == 0 && tid < 16) {   // zero sentinel row N in every chunk slice
    v8hf z;
    #pragma unroll
    for (int j = 0; j < 8; j++) z[j] = (_Float16)0.f;
    int c = tid >> 1, h = tid & 1;
    *(v8hf*)(g16 + ((size_t)c * (N + 1) + N) * CFEAT + h * 8) = z;
  }

  if constexpr (sizeof(AT) == 4) {   // fp32 input: load + cast
    #pragma unroll
    for (int i = 0; i < 8; i++) {
      int idx = tid + i * 256;       // 0..2047
      int row = idx >> 5;
      int c4 = idx & 31;
      int gr = row0 + row; gr = (gr < N) ? gr : (N - 1);
      float4 v = *(const float4*)((const float*)A + (size_t)gr * NFEAT + c4 * 4);
      _Float16* p = &As[row][c4 * 4];
      p[0] = (_Float16)v.x; p[1] = (_Float16)v.y;
      p[2] = (_Float16)v.z; p[3] = (_Float16)v.w;
    }
  } else {                           // fp16 input: straight copy
    #pragma unroll
    for (int i = 0; i < 4; i++) {
      int idx = tid + i * 256;
      int row = idx >> 4;
      int c8 = idx & 15;
      int gr = row0 + row; gr = (gr < N) ? gr : (N - 1);
      *(uint4*)&As[row][c8 * 8] =
          *(const uint4*)((const _Float16*)A + (size_t)gr * NFEAT + c8 * 8);
    }
  }
  #pragma unroll
  for (int i = 0; i < 8; i++) {
    int idx = tid + i * 256;
    int row = idx >> 4;
    int c8 = idx & 15;
    *(uint4*)&Ws[row][c8 * 8] = *(const uint4*)(Wt + (size_t)row * 128 + c8 * 8);
  }
  __syncthreads();

  const int wv = tid >> 6;
  const int lane = tid & 63;
  const int m = lane & 15;
  const int q = lane >> 4;

  v4f acc[8] = {};
  const _Float16* arow = &As[wv * 16 + m][0];
  #pragma unroll
  for (int kt = 0; kt < 4; kt++) {
    v8hf af = *(const v8hf*)(arow + kt * 32 + q * 8);
    #pragma unroll
    for (int ct = 0; ct < 8; ct++) {
      v8hf bf = *(const v8hf*)(&Ws[ct * 16 + m][kt * 32 + q * 8]);
      acc[ct] = __builtin_amdgcn_mfma_f32_16x16x32_f16(af, bf, acc[ct], 0, 0, 0);
    }
  }

  int nd[4]; float dv[4];
  #pragma unroll
  for (int r = 0; r < 4; r++) {
    nd[r] = row0 + wv * 16 + q * 4 + r;
    int c = (nd[r] < N) ? nd[r] : (N - 1);
    dv[r] = dinv[c];
  }
  #pragma unroll
  for (int ct = 0; ct < 8; ct++) {
    _Float16* gout = g16 + (size_t)ct * (N + 1) * CFEAT;
    #pragma unroll
    for (int r = 0; r < 4; r++)
      if (nd[r] < N)
        gout[(size_t)nd[r] * CFEAT + m] = (_Float16)(acc[ct][r] * dv[r]);
  }
}

// ---------------- feature-chunked, XCD-pinned aggregation --------------------
// chunk = blockIdx % 8 -> XCD (round-robin dispatch). Each chunk's gather
// slice is 3.2 MB, L2-resident per XCD. Wave layout: 4 nodes x 8 edge slots
// x 2 half-rows (16 B). Uniform trip count = wave-max over the 4 nodes;
// out-of-degree slots gather the zero sentinel row N (hot line, ~free).
__global__ __launch_bounds__(256) void k_agg(
    const _Float16* __restrict__ g, const float* __restrict__ dinv,
    const int* __restrict__ base, const int* __restrict__ ssrc,
    const float* __restrict__ bias, _Float16* __restrict__ hB, int N) {
  const int chunk = blockIdx.x & 7;
  const int nblk = blockIdx.x >> 3;
  const int lane = threadIdx.x & 63;
  const int wave = threadIdx.x >> 6;
  const int half = lane & 1;          // which 8 of the 16 chunk features
  const int slot = (lane >> 1) & 7;   // edge slot 0..7
  const int n = nblk * 16 + wave * 4 + (lane >> 4);

  const _Float16* gc = g + (size_t)chunk * (N + 1) * CFEAT;

  int b0 = 0, b1 = 0;
  if (n < N) { b0 = base[n]; b1 = base[n + 1]; }
  int nit = (b1 - b0 + 7) >> 3;
  { int t = __shfl_xor(nit, 16, 64); nit = (t > nit) ? t : nit; }
  { int t = __shfl_xor(nit, 32, 64); nit = (t > nit) ? t : nit; }

  float acc[8] = {};
  if (nit > 0) {
    // iter 0 index + gather
    int p = b0 + slot;
    int i = ssrc[p];
    i = (p < b1) ? i : N;
    v8hf r = *(const v8hf*)(gc + (size_t)i * CFEAT + half * 8);
    // iter 1 index
    int j = N;
    if (nit > 1) {
      int pn = b0 + 8 + slot;
      j = ssrc[pn];
      j = (pn < b1) ? j : N;
    }
    for (int it = 1; ; ++it) {
      bool more = (it < nit);           // wave-uniform
      v8hf rn; int jn = N;
      if (more) {                        // issue next gather before consuming
        rn = *(const v8hf*)(gc + (size_t)j * CFEAT + half * 8);
        if (it + 1 < nit) {              // prefetch iter+1 indices
          int pn = b0 + (it + 1) * 8 + slot;
          jn = ssrc[pn];
          jn = (pn < b1) ? jn : N;
        }
      }
      #pragma unroll
      for (int jj = 0; jj < 8; jj++) acc[jj] += (float)r[jj];
      if (!more) break;
      r = rn; j = jn;
    }
  }

  // butterfly reduce over the 8 edge slots (lane bits 1..3)
  #pragma unroll
  for (int jj = 0; jj < 8; jj++) {
    acc[jj] += __shfl_xor(acc[jj], 2, 64);
    acc[jj] += __shfl_xor(acc[jj], 4, 64);
    acc[jj] += __shfl_xor(acc[jj], 8, 64);
  }
  if (n < N && (lane & 14) == 0) {      // slot==0 lanes: one per (node, half)
    float dvn = dinv[n];
    const float* bp = bias + chunk * CFEAT + half * 8;
    v8hf o;
    #pragma unroll
    for (int jj = 0; jj < 8; jj++)
      o[jj] = (_Float16)fmaxf(acc[jj] * dvn + bp[jj], 0.f);
    *(v8hf*)(hB + (size_t)n * NFEAT + chunk * CFEAT + half * 8) = o;
  }
}

// ---------------- layer-2 agg fused with final linear ------------------------
// Same chunked gather; cross-chunk combine via one fp32 atomicAdd per node.
__global__ __launch_bounds__(256) void k_agg_final(
    const _Float16* __restrict__ g, const float* __restrict__ dinv,
    const int* __restrict__ base, const int* __restrict__ ssrc,
    const float* __restrict__ bias, const float* __restrict__ wlin,
    const float* __restrict__ blin, float* __restrict__ out, int N) {
  const int chunk = blockIdx.x & 7;
  const int nblk = blockIdx.x >> 3;
  const int lane = threadIdx.x & 63;
  const int wave = threadIdx.x >> 6;
  const int half = lane & 1;
  const int slot = (lane >> 1) & 7;
  const int n = nblk * 16 + wave * 4 + (lane >> 4);

  const _Float16* gc = g + (size_t)chunk * (N + 1) * CFEAT;

  int b0 = 0, b1 = 0;
  if (n < N) { b0 = base[n]; b1 = base[n + 1]; }
  int nit = (b1 - b0 + 7) >> 3;
  { int t = __shfl_xor(nit, 16, 64); nit = (t > nit) ? t : nit; }
  { int t = __shfl_xor(nit, 32, 64); nit = (t > nit) ? t : nit; }

  float acc[8] = {};
  if (nit > 0) {
    int p = b0 + slot;
    int i = ssrc[p];
    i = (p < b1) ? i : N;
    v8hf r = *(const v8hf*)(gc + (size_t)i * CFEAT + half * 8);
    int j = N;
    if (nit > 1) {
      int pn = b0 + 8 + slot;
      j = ssrc[pn];
      j = (pn < b1) ? j : N;
    }
    for (int it = 1; ; ++it) {
      bool more = (it < nit);
      v8hf rn; int jn = N;
      if (more) {
        rn = *(const v8hf*)(gc + (size_t)j * CFEAT + half * 8);
        if (it + 1 < nit) {
          int pn = b0 + (it + 1) * 8 + slot;
          jn = ssrc[pn];
          jn = (pn < b1) ? jn : N;
        }
      }
      #pragma unroll
      for (int jj = 0; jj < 8; jj++) acc[jj] += (float)r[jj];
      if (!more) break;
      r = rn; j = jn;
    }
  }

  #pragma unroll
  for (int jj = 0; jj < 8; jj++) {
    acc[jj] += __shfl_xor(acc[jj], 2, 64);
    acc[jj] += __shfl_xor(acc[jj], 4, 64);
    acc[jj] += __shfl_xor(acc[jj], 8, 64);
  }
  // all lanes now hold their half's full slot-sum (butterfly)
  float pv = 0.f;
  if (n < N) {
    float dvn = dinv[n];
    const float* bp = bias + chunk * CFEAT + half * 8;
    const float* wp = wlin + chunk * CFEAT + half * 8;
    #pragma unroll
    for (int jj = 0; jj < 8; jj++)
      pv += fmaxf(acc[jj] * dvn + bp[jj], 0.f) * wp[jj];
  }
  pv += __shfl_xor(pv, 1, 64);          // combine halves
  if (n < N && (lane & 15) == 0) {
    if (chunk == 0) pv += blin[0];
    atomicAdd(out + n, pv);
  }
}

extern "C" void kernel_launch(void* const* d_in, const int* in_sizes, int n_in,
                              void* d_out, int out_size, void* d_ws, size_t ws_size,
                              hipStream_t stream) {
  const float* x    = (const float*)d_in[0];
  const int*   ei   = (const int*)d_in[1];
  const float* W1   = (const float*)d_in[2];
  const float* b1   = (const float*)d_in[3];
  const float* W2   = (const float*)d_in[4];
  const float* b2   = (const float*)d_in[5];
  const float* Wlin = (const float*)d_in[6];
  const float* blin = (const float*)d_in[7];
  const int N = in_sizes[0] / NFEAT;
  const int E = in_sizes[1] / 2;
  const int* src = ei;
  const int* dst = ei + E;
  const int Etot = E + N;   // real edges + self edges

  // workspace layout (4B units)
  int* ws_i = (int*)d_ws;
  size_t off = 0;
  int* deg      = ws_i + off; off += N;
  int* base     = ws_i + off; off += (size_t)N + 1;
  off = (off + 3) & ~(size_t)3;
  int* partials = ws_i + off; off += 128;
  int* ssrc     = ws_i + off; off += Etot + 64;  // slack for uniform-trip tails
  float* dinv   = (float*)(ws_i + off); off += N;
  off = (off + 3) & ~(size_t)3;
  _Float16* Wt1 = (_Float16*)(ws_i + off); off += 8192;
  _Float16* Wt2 = (_Float16*)(ws_i + off); off += 8192;
  _Float16* g16 = (_Float16*)(ws_i + off); off += (size_t)(N + 1) * 64;  // chunk-major + sentinel
  _Float16* hB  = (_Float16*)(ws_i + off); off += (size_t)N * 64;
  int* rank     = (int*)g16;   // Etot ints, consumed by k_scatter before g16 written

  hipMemsetAsync(deg, 0, (size_t)N * sizeof(int), stream);
  hipMemsetAsync(d_out, 0, (size_t)N * sizeof(float), stream);

  const int tpbE = 256;
  const int gE = (Etot + 32768 + tpbE - 1) / tpbE;
  k_deg_rank_w<<<gE, tpbE, 0, stream>>>(dst, deg, rank, E, N, W1, W2, Wt1, Wt2);

  const int nb = (N + 1 + 1023) / 1024;
  k_scan_blocks<<<nb, 1024, 0, stream>>>(deg, base, partials, N);
  k_scan_partials<<<1, 128, 0, stream>>>(partials, nb);
  k_finalize_base<<<((N + 1) + 255) / 256, 256, 0, stream>>>(base, partials, deg, dinv, N);
  k_scatter<<<(Etot + tpbE - 1) / tpbE, tpbE, 0, stream>>>(src, dst, rank, base, ssrc, E, N);

  const int gg = (N + 63) / 64;
  const int ga = NCHUNK * ((N + 15) >> 4);   // 8 chunk-blocks per 16-node group
  // layer 1
  k_gemm_mfma<float><<<gg, 256, 0, stream>>>(x, Wt1, dinv, g16, N);
  k_agg<<<ga, 256, 0, stream>>>(g16, dinv, base, ssrc, b1, hB, N);
  // layer 2 + fused final linear
  k_gemm_mfma<_Float16><<<gg, 256, 0, stream>>>(hB, Wt2, dinv, g16, N);
  k_agg_final<<<ga, 256, 0, stream>>>(g16, dinv, base, ssrc, b2,
                                      Wlin, blin, (float*)d_out, N);
}

// Round 2
// 384.243 us; speedup vs baseline: 1.1417x; 1.1417x over previous
//
#include <hip/hip_runtime.h>
#include <hip/hip_fp16.h>

#define NFEAT 128

typedef _Float16 v8hf __attribute__((ext_vector_type(8)));
typedef float v4f __attribute__((ext_vector_type(4)));

// ------- degree histogram + per-edge rank (incl. self edges) + W prep --------
__global__ void k_deg_rank_w(const int* __restrict__ dst, int* __restrict__ deg,
                             int* __restrict__ rank, int E, int N,
                             const float* __restrict__ W1, const float* __restrict__ W2,
                             _Float16* __restrict__ Wt1, _Float16* __restrict__ Wt2) {
  int e = blockIdx.x * blockDim.x + threadIdx.x;
  if (e < E) rank[e] = atomicAdd(&deg[dst[e]], 1);
  else if (e < E + N) rank[e] = atomicAdd(&deg[e - E], 1);
  else if (e < E + N + 32768) {
    int idx = e - E - N;             // 0..32767
    const float* W = (idx < 16384) ? W1 : W2;
    _Float16* Wt = (idx < 16384) ? Wt1 : Wt2;
    int i = idx & 16383;
    int k = i >> 7, n = i & 127;
    Wt[n * 128 + k] = (_Float16)W[k * 128 + n];
  }
}

// ---------------- 2-level exclusive scan over degrees ------------------------
__global__ __launch_bounds__(1024) void k_scan_blocks(const int* __restrict__ deg,
    int* __restrict__ base, int* __restrict__ partials, int n) {
  __shared__ int buf[1024];
  int tid = threadIdx.x;
  int i = blockIdx.x * 1024 + tid;
  int v = (i < n) ? deg[i] : 0;
  buf[tid] = v;
  __syncthreads();
  #pragma unroll
  for (int off = 1; off < 1024; off <<= 1) {
    int t = (tid >= off) ? buf[tid - off] : 0;
    __syncthreads();
    buf[tid] += t;
    __syncthreads();
  }
  if (i <= n) base[i] = buf[tid] - v;
  if (tid == 1023) partials[blockIdx.x] = buf[tid];
}

__global__ void k_scan_partials(int* __restrict__ partials, int nb) {
  __shared__ int buf[128];
  int tid = threadIdx.x;
  int v = (tid < nb) ? partials[tid] : 0;
  buf[tid] = v;
  __syncthreads();
  #pragma unroll
  for (int off = 1; off < 128; off <<= 1) {
    int t = (tid >= off) ? buf[tid - off] : 0;
    __syncthreads();
    buf[tid] += t;
    __syncthreads();
  }
  if (tid < nb) partials[tid] = buf[tid] - v;
}

__global__ void k_finalize_base(int* __restrict__ base, const int* __restrict__ partials,
    const int* __restrict__ deg, float* __restrict__ dinv, int n) {
  int i = blockIdx.x * blockDim.x + threadIdx.x;
  if (i <= n) {
    base[i] += partials[i >> 10];
    if (i < n) dinv[i] = rsqrtf((float)deg[i]);   // deg already includes self
  }
}

__global__ void k_scatter(const int* __restrict__ src, const int* __restrict__ dst,
    const int* __restrict__ rank, const int* __restrict__ base,
    int* __restrict__ ssrc, int E, int N) {
  int e = blockIdx.x * blockDim.x + threadIdx.x;
  if (e < E) ssrc[base[dst[e]] + rank[e]] = src[e];
  else if (e < E + N) { int n = e - E; ssrc[base[n] + rank[e]] = n; }
}

// ---------------- MFMA fp16 GEMM: g16[r][:] = half((A[r][:] @ W) * dinv[r]) --
template <typename AT>
__global__ __launch_bounds__(256) void k_gemm_mfma(
    const AT* __restrict__ A, const _Float16* __restrict__ Wt,
    const float* __restrict__ dinv, _Float16* __restrict__ g16, int N) {
  __shared__ _Float16 As[64][136];
  __shared__ _Float16 Ws[128][136];
  const int tid = threadIdx.x;
  const int row0 = blockIdx.x * 64;

  if (blockIdx.x == 0 && tid < 16) {   // zero sentinel row N
    v8hf z;
    #pragma unroll
    for (int j = 0; j < 8; j++) z[j] = (_Float16)0.f;
    *(v8hf*)(g16 + (size_t)N * NFEAT + tid * 8) = z;
  }

  if constexpr (sizeof(AT) == 4) {   // fp32 input: load + cast
    #pragma unroll
    for (int i = 0; i < 8; i++) {
      int idx = tid + i * 256;       // 0..2047
      int row = idx >> 5;
      int c4 = idx & 31;
      int gr = row0 + row; gr = (gr < N) ? gr : (N - 1);
      float4 v = *(const float4*)((const float*)A + (size_t)gr * NFEAT + c4 * 4);
      _Float16* p = &As[row][c4 * 4];
      p[0] = (_Float16)v.x; p[1] = (_Float16)v.y;
      p[2] = (_Float16)v.z; p[3] = (_Float16)v.w;
    }
  } else {                           // fp16 input: straight copy
    #pragma unroll
    for (int i = 0; i < 4; i++) {
      int idx = tid + i * 256;
      int row = idx >> 4;
      int c8 = idx & 15;
      int gr = row0 + row; gr = (gr < N) ? gr : (N - 1);
      *(uint4*)&As[row][c8 * 8] =
          *(const uint4*)((const _Float16*)A + (size_t)gr * NFEAT + c8 * 8);
    }
  }
  #pragma unroll
  for (int i = 0; i < 8; i++) {
    int idx = tid + i * 256;
    int row = idx >> 4;
    int c8 = idx & 15;
    *(uint4*)&Ws[row][c8 * 8] = *(const uint4*)(Wt + (size_t)row * 128 + c8 * 8);
  }
  __syncthreads();

  const int wv = tid >> 6;
  const int lane = tid & 63;
  const int m = lane & 15;
  const int q = lane >> 4;

  v4f acc[8] = {};
  const _Float16* arow = &As[wv * 16 + m][0];
  #pragma unroll
  for (int kt = 0; kt < 4; kt++) {
    v8hf af = *(const v8hf*)(arow + kt * 32 + q * 8);
    #pragma unroll
    for (int ct = 0; ct < 8; ct++) {
      v8hf bf = *(const v8hf*)(&Ws[ct * 16 + m][kt * 32 + q * 8]);
      acc[ct] = __builtin_amdgcn_mfma_f32_16x16x32_f16(af, bf, acc[ct], 0, 0, 0);
    }
  }

  int nd[4]; float dv[4];
  #pragma unroll
  for (int r = 0; r < 4; r++) {
    nd[r] = row0 + wv * 16 + q * 4 + r;
    int c = (nd[r] < N) ? nd[r] : (N - 1);
    dv[r] = dinv[c];
  }
  #pragma unroll
  for (int ct = 0; ct < 8; ct++)
    #pragma unroll
    for (int r = 0; r < 4; r++)
      if (nd[r] < N)
        g16[(size_t)nd[r] * NFEAT + ct * 16 + m] = (_Float16)(acc[ct][r] * dv[r]);
}

// ---------------- agg: wave per node, deep upfront prefetch ------------------
// Lane = (gq = lane>>4: edge slot, l = lane&15: features l*8..l*8+7).
// Up to 4 iterations (32 edges = 8 gather instrs + 8 index loads) are issued
// IN FLIGHT before the first consume -> per-wave critical path is ~1 memory
// round trip instead of ~3. nit is wave-uniform (one node per wave). Rare
// nit>4 nodes fall through to the proven depth-2 rolling loop. Tail edges
// clamp to zero sentinel row N.
__global__ __launch_bounds__(256) void k_agg(
    const _Float16* __restrict__ g, const float* __restrict__ dinv,
    const int* __restrict__ base, const int* __restrict__ ssrc,
    const float* __restrict__ bias, _Float16* __restrict__ hB, int N) {
  const int lane = threadIdx.x & 63;
  const int n = blockIdx.x * 4 + (threadIdx.x >> 6);
  if (n >= N) return;
  const int gq = lane >> 4;
  const int l = lane & 15;
  const int b0 = base[n], b1 = base[n + 1];
  const int nit = (b1 - b0 + 7) >> 3;     // >= 1 (self-loop)

  v8hf r0a, r0b, r1a, r1b, r2a, r2b, r3a, r3b;
  // iter 0 (always)
  {
    int p0 = b0 + gq, p1 = b0 + 4 + gq;
    int i0 = ssrc[p0], i1 = ssrc[p1];
    i0 = (p0 < b1) ? i0 : N;
    i1 = (p1 < b1) ? i1 : N;
    r0a = *(const v8hf*)(g + (size_t)i0 * NFEAT + l * 8);
    r0b = *(const v8hf*)(g + (size_t)i1 * NFEAT + l * 8);
  }
  if (nit > 1) {
    int e = b0 + 8;
    int p0 = e + gq, p1 = e + 4 + gq;
    int i0 = ssrc[p0], i1 = ssrc[p1];
    i0 = (p0 < b1) ? i0 : N;
    i1 = (p1 < b1) ? i1 : N;
    r1a = *(const v8hf*)(g + (size_t)i0 * NFEAT + l * 8);
    r1b = *(const v8hf*)(g + (size_t)i1 * NFEAT + l * 8);
  }
  if (nit > 2) {
    int e = b0 + 16;
    int p0 = e + gq, p1 = e + 4 + gq;
    int i0 = ssrc[p0], i1 = ssrc[p1];
    i0 = (p0 < b1) ? i0 : N;
    i1 = (p1 < b1) ? i1 : N;
    r2a = *(const v8hf*)(g + (size_t)i0 * NFEAT + l * 8);
    r2b = *(const v8hf*)(g + (size_t)i1 * NFEAT + l * 8);
  }
  if (nit > 3) {
    int e = b0 + 24;
    int p0 = e + gq, p1 = e + 4 + gq;
    int i0 = ssrc[p0], i1 = ssrc[p1];
    i0 = (p0 < b1) ? i0 : N;
    i1 = (p1 < b1) ? i1 : N;
    r3a = *(const v8hf*)(g + (size_t)i0 * NFEAT + l * 8);
    r3b = *(const v8hf*)(g + (size_t)i1 * NFEAT + l * 8);
  }

  float acc[8] = {};
  #pragma unroll
  for (int j = 0; j < 8; j++) acc[j] += (float)r0a[j] + (float)r0b[j];
  if (nit > 1) {
    #pragma unroll
    for (int j = 0; j < 8; j++) acc[j] += (float)r1a[j] + (float)r1b[j];
  }
  if (nit > 2) {
    #pragma unroll
    for (int j = 0; j < 8; j++) acc[j] += (float)r2a[j] + (float)r2b[j];
  }
  if (nit > 3) {
    #pragma unroll
    for (int j = 0; j < 8; j++) acc[j] += (float)r3a[j] + (float)r3b[j];
  }

  if (nit > 4) {                          // rare long-tail: depth-2 rolling loop
    int e = b0 + 32;
    int p0 = e + gq, p1 = e + 4 + gq;
    int i0 = ssrc[p0], i1 = ssrc[p1];
    i0 = (p0 < b1) ? i0 : N;
    i1 = (p1 < b1) ? i1 : N;
    v8hf r0 = *(const v8hf*)(g + (size_t)i0 * NFEAT + l * 8);
    v8hf r1 = *(const v8hf*)(g + (size_t)i1 * NFEAT + l * 8);
    int e2 = e + 8;
    int j0 = N, j1 = N;
    if (e2 < b1) {
      int q0 = e2 + gq, q1 = e2 + 4 + gq;
      j0 = ssrc[q0]; j1 = ssrc[q1];
      j0 = (q0 < b1) ? j0 : N;
      j1 = (q1 < b1) ? j1 : N;
    }
    while (true) {
      bool more = (e2 < b1);
      v8hf s0, s1;
      if (more) {
        s0 = *(const v8hf*)(g + (size_t)j0 * NFEAT + l * 8);
        s1 = *(const v8hf*)(g + (size_t)j1 * NFEAT + l * 8);
      }
      int e3 = e2 + 8;
      int c0 = N, c1 = N;
      if (e3 < b1) {
        int q0 = e3 + gq, q1 = e3 + 4 + gq;
        c0 = ssrc[q0]; c1 = ssrc[q1];
        c0 = (q0 < b1) ? c0 : N;
        c1 = (q1 < b1) ? c1 : N;
      }
      #pragma unroll
      for (int j = 0; j < 8; j++) acc[j] += (float)r0[j] + (float)r1[j];
      if (!more) break;
      r0 = s0; r1 = s1;
      j0 = c0; j1 = c1;
      e2 = e3;
    }
  }

  #pragma unroll
  for (int j = 0; j < 8; j++) {
    acc[j] += __shfl_xor(acc[j], 16, 64);
    acc[j] += __shfl_xor(acc[j], 32, 64);
  }
  if (gq == 0) {
    float dvn = dinv[n];
    const float* bp = bias + l * 8;
    float4 bb0 = *(const float4*)(bp);
    float4 bb1 = *(const float4*)(bp + 4);
    float bv[8] = {bb0.x, bb0.y, bb0.z, bb0.w, bb1.x, bb1.y, bb1.z, bb1.w};
    v8hf o;
    #pragma unroll
    for (int j = 0; j < 8; j++)
      o[j] = (_Float16)fmaxf(acc[j] * dvn + bv[j], 0.f);
    *(v8hf*)(hB + (size_t)n * NFEAT + l * 8) = o;
  }
}

// ---------------- layer-2 agg fused with final linear (same pipeline) --------
__global__ __launch_bounds__(256) void k_agg_final(
    const _Float16* __restrict__ g, const float* __restrict__ dinv,
    const int* __restrict__ base, const int* __restrict__ ssrc,
    const float* __restrict__ bias, const float* __restrict__ wlin,
    const float* __restrict__ blin, float* __restrict__ out, int N) {
  const int lane = threadIdx.x & 63;
  const int n = blockIdx.x * 4 + (threadIdx.x >> 6);
  if (n >= N) return;
  const int gq = lane >> 4;
  const int l = lane & 15;
  const int b0 = base[n], b1 = base[n + 1];
  const int nit = (b1 - b0 + 7) >> 3;

  v8hf r0a, r0b, r1a, r1b, r2a, r2b, r3a, r3b;
  {
    int p0 = b0 + gq, p1 = b0 + 4 + gq;
    int i0 = ssrc[p0], i1 = ssrc[p1];
    i0 = (p0 < b1) ? i0 : N;
    i1 = (p1 < b1) ? i1 : N;
    r0a = *(const v8hf*)(g + (size_t)i0 * NFEAT + l * 8);
    r0b = *(const v8hf*)(g + (size_t)i1 * NFEAT + l * 8);
  }
  if (nit > 1) {
    int e = b0 + 8;
    int p0 = e + gq, p1 = e + 4 + gq;
    int i0 = ssrc[p0], i1 = ssrc[p1];
    i0 = (p0 < b1) ? i0 : N;
    i1 = (p1 < b1) ? i1 : N;
    r1a = *(const v8hf*)(g + (size_t)i0 * NFEAT + l * 8);
    r1b = *(const v8hf*)(g + (size_t)i1 * NFEAT + l * 8);
  }
  if (nit > 2) {
    int e = b0 + 16;
    int p0 = e + gq, p1 = e + 4 + gq;
    int i0 = ssrc[p0], i1 = ssrc[p1];
    i0 = (p0 < b1) ? i0 : N;
    i1 = (p1 < b1) ? i1 : N;
    r2a = *(const v8hf*)(g + (size_t)i0 * NFEAT + l * 8);
    r2b = *(const v8hf*)(g + (size_t)i1 * NFEAT + l * 8);
  }
  if (nit > 3) {
    int e = b0 + 24;
    int p0 = e + gq, p1 = e + 4 + gq;
    int i0 = ssrc[p0], i1 = ssrc[p1];
    i0 = (p0 < b1) ? i0 : N;
    i1 = (p1 < b1) ? i1 : N;
    r3a = *(const v8hf*)(g + (size_t)i0 * NFEAT + l * 8);
    r3b = *(const v8hf*)(g + (size_t)i1 * NFEAT + l * 8);
  }

  float acc[8] = {};
  #pragma unroll
  for (int j = 0; j < 8; j++) acc[j] += (float)r0a[j] + (float)r0b[j];
  if (nit > 1) {
    #pragma unroll
    for (int j = 0; j < 8; j++) acc[j] += (float)r1a[j] + (float)r1b[j];
  }
  if (nit > 2) {
    #pragma unroll
    for (int j = 0; j < 8; j++) acc[j] += (float)r2a[j] + (float)r2b[j];
  }
  if (nit > 3) {
    #pragma unroll
    for (int j = 0; j < 8; j++) acc[j] += (float)r3a[j] + (float)r3b[j];
  }

  if (nit > 4) {
    int e = b0 + 32;
    int p0 = e + gq, p1 = e + 4 + gq;
    int i0 = ssrc[p0], i1 = ssrc[p1];
    i0 = (p0 < b1) ? i0 : N;
    i1 = (p1 < b1) ? i1 : N;
    v8hf r0 = *(const v8hf*)(g + (size_t)i0 * NFEAT + l * 8);
    v8hf r1 = *(const v8hf*)(g + (size_t)i1 * NFEAT + l * 8);
    int e2 = e + 8;
    int j0 = N, j1 = N;
    if (e2 < b1) {
      int q0 = e2 + gq, q1 = e2 + 4 + gq;
      j0 = ssrc[q0]; j1 = ssrc[q1];
      j0 = (q0 < b1) ? j0 : N;
      j1 = (q1 < b1) ? j1 : N;
    }
    while (true) {
      bool more = (e2 < b1);
      v8hf s0, s1;
      if (more) {
        s0 = *(const v8hf*)(g + (size_t)j0 * NFEAT + l * 8);
        s1 = *(const v8hf*)(g + (size_t)j1 * NFEAT + l * 8);
      }
      int e3 = e2 + 8;
      int c0 = N, c1 = N;
      if (e3 < b1) {
        int q0 = e3 + gq, q1 = e3 + 4 + gq;
        c0 = ssrc[q0]; c1 = ssrc[q1];
        c0 = (q0 < b1) ? c0 : N;
        c1 = (q1 < b1) ? c1 : N;
      }
      #pragma unroll
      for (int j = 0; j < 8; j++) acc[j] += (float)r0[j] + (float)r1[j];
      if (!more) break;
      r0 = s0; r1 = s1;
      j0 = c0; j1 = c1;
      e2 = e3;
    }
  }

  #pragma unroll
  for (int j = 0; j < 8; j++) {
    acc[j] += __shfl_xor(acc[j], 16, 64);
    acc[j] += __shfl_xor(acc[j], 32, 64);
  }
  float dvn = dinv[n];
  const float* bp = bias + l * 8;
  const float* wp = wlin + l * 8;
  float4 bb0 = *(const float4*)(bp);
  float4 bb1 = *(const float4*)(bp + 4);
  float4 wl0 = *(const float4*)(wp);
  float4 wl1 = *(const float4*)(wp + 4);
  float bv[8] = {bb0.x, bb0.y, bb0.z, bb0.w, bb1.x, bb1.y, bb1.z, bb1.w};
  float wv[8] = {wl0.x, wl0.y, wl0.z, wl0.w, wl1.x, wl1.y, wl1.z, wl1.w};
  float pv = 0.f;
  #pragma unroll
  for (int j = 0; j < 8; j++)
    pv += fmaxf(acc[j] * dvn + bv[j], 0.f) * wv[j];
  pv += __shfl_xor(pv, 1, 64);
  pv += __shfl_xor(pv, 2, 64);
  pv += __shfl_xor(pv, 4, 64);
  pv += __shfl_xor(pv, 8, 64);
  if (lane == 0) out[n] = pv + blin[0];
}

extern "C" void kernel_launch(void* const* d_in, const int* in_sizes, int n_in,
                              void* d_out, int out_size, void* d_ws, size_t ws_size,
                              hipStream_t stream) {
  const float* x    = (const float*)d_in[0];
  const int*   ei   = (const int*)d_in[1];
  const float* W1   = (const float*)d_in[2];
  const float* b1   = (const float*)d_in[3];
  const float* W2   = (const float*)d_in[4];
  const float* b2   = (const float*)d_in[5];
  const float* Wlin = (const float*)d_in[6];
  const float* blin = (const float*)d_in[7];
  const int N = in_sizes[0] / NFEAT;
  const int E = in_sizes[1] / 2;
  const int* src = ei;
  const int* dst = ei + E;
  const int Etot = E + N;   // real edges + self edges

  // workspace layout (4B units)
  int* ws_i = (int*)d_ws;
  size_t off = 0;
  int* deg      = ws_i + off; off += N;
  int* base     = ws_i + off; off += (size_t)N + 1;
  off = (off + 3) & ~(size_t)3;
  int* partials = ws_i + off; off += 128;
  int* ssrc     = ws_i + off; off += Etot + 8;   // +8 slack for tail loads
  float* dinv   = (float*)(ws_i + off); off += N;
  off = (off + 3) & ~(size_t)3;
  _Float16* Wt1 = (_Float16*)(ws_i + off); off += 8192;
  _Float16* Wt2 = (_Float16*)(ws_i + off); off += 8192;
  _Float16* g16 = (_Float16*)(ws_i + off); off += (size_t)(N + 1) * 64;  // +sentinel
  _Float16* hB  = (_Float16*)(ws_i + off); off += (size_t)N * 64;
  int* rank     = (int*)g16;   // Etot ints, consumed by k_scatter before g16 written

  hipMemsetAsync(deg, 0, (size_t)N * sizeof(int), stream);

  const int tpbE = 256;
  const int gE = (Etot + 32768 + tpbE - 1) / tpbE;
  k_deg_rank_w<<<gE, tpbE, 0, stream>>>(dst, deg, rank, E, N, W1, W2, Wt1, Wt2);

  const int nb = (N + 1 + 1023) / 1024;
  k_scan_blocks<<<nb, 1024, 0, stream>>>(deg, base, partials, N);
  k_scan_partials<<<1, 128, 0, stream>>>(partials, nb);
  k_finalize_base<<<((N + 1) + 255) / 256, 256, 0, stream>>>(base, partials, deg, dinv, N);
  k_scatter<<<(Etot + tpbE - 1) / tpbE, tpbE, 0, stream>>>(src, dst, rank, base, ssrc, E, N);

  const int gg = (N + 63) / 64;
  const int ga = (N + 3) / 4;
  // layer 1
  k_gemm_mfma<float><<<gg, 256, 0, stream>>>(x, Wt1, dinv, g16, N);
  k_agg<<<ga, 256, 0, stream>>>(g16, dinv, base, ssrc, b1, hB, N);
  // layer 2 + fused final linear
  k_gemm_mfma<_Float16><<<gg, 256, 0, stream>>>(hB, Wt2, dinv, g16, N);
  k_agg_final<<<ga, 256, 0, stream>>>(g16, dinv, base, ssrc, b2,
                                      Wlin, blin, (float*)d_out, N);
}